// Round 20
// baseline (325.693 us; speedup 1.0000x reference)
//
#include <hip/hip_runtime.h>
#include <hip/hip_bf16.h>

// ---------------------------------------------------------------------------
// PPO Actor-Critic GNN on MI355X.
// Round 20: k2a is invariant to occupancy (28%->39% gave same 99us) -> its
// ~1.7TB/s on ~165MB is structural; attack the hidden k2b instead.
// k2b restructured: ONE 1024-thread block per 4096-node bucket (123 x 16
// waves), 32KB LDS acc, single S2 output (4MB) - removes the 4-replica
// write/read (24MB round trip) and doubles per-CU waves for the gather chain.
// k2a = counting-sort scatter (r18); k3 = fp8 MFMA (r16), now nsl=1;
// scalar reductions via partials (no same-line global atomics, r10/11).
// ---------------------------------------------------------------------------

typedef unsigned int u32;
typedef unsigned long long u64;
typedef long long i64t;
typedef __attribute__((ext_vector_type(4))) float f32x4;

#define BP_STRIDE 16   // bucketPos padding: 16 u32 = 64B per counter
#define CHUNK 8192

__device__ __forceinline__ float sigf(float x) { return 1.0f / (1.0f + __expf(-x)); }

__device__ __forceinline__ float waveReduceSum(float v) {
#pragma unroll
    for (int off = 32; off > 0; off >>= 1) v += __shfl_down(v, off, 64);
    return v;
}
__device__ __forceinline__ float waveReduceMax(float v) {
#pragma unroll
    for (int off = 32; off > 0; off >>= 1) v = fmaxf(v, __shfl_down(v, off, 64));
    return v;
}

// accum layout (floats):
// [0] max|hop| [1] max|cos| [2] max|rd| [3] max|ett|
// [4] sum ct   [5] sum hop  [6] sum rd
// [7] sum exp(policy)
// [8] sum x_ct  [9] sum x_hop_norm  [10] sum x_rd_norm

__global__ __launch_bounds__(256) void k1_prep(
    const float* __restrict__ hop, const float* __restrict__ rd,
    const float* __restrict__ ett, const float* __restrict__ ct,
    const float* __restrict__ c2n, const float* __restrict__ c2t,
    float4* __restrict__ featA, u64* __restrict__ packed,
    float* __restrict__ partials, int n)
{
    int i = blockIdx.x * blockDim.x + threadIdx.x;
    float ah = 0.f, ac = 0.f, ar = 0.f, ae = 0.f, sc = 0.f, sh = 0.f, sr = 0.f;
    if (i < n) {
        float h = hop[i], r = rd[i], e = ett[i], c = ct[i];
        float ax = c2n[3*i+0], ay = c2n[3*i+1], az = c2n[3*i+2];
        float bx = c2t[3*i+0], by = c2t[3*i+1], bz = c2t[3*i+2];
        float dot = ax*bx + ay*by + az*bz;
        float na = fmaxf(sqrtf(ax*ax + ay*ay + az*az), 1e-6f);
        float nb = fmaxf(sqrtf(bx*bx + by*by + bz*bz), 1e-6f);
        float cs = dot / (na * nb);
        featA[i] = make_float4(h, cs, r, e);

        // single-u64 fixed-point pack, scale 16
        // fields: ct 11b | hop 11b | cos+1 12b | rd 11b | ett 11b | deg 8b
        u64 qc = (u64)(u32)rintf(c * (16.0f/1440.0f));
        u64 qh = (u64)(u32)rintf(h * 16.0f);
        u64 qs = (u64)(u32)rintf((cs + 1.0f) * 16.0f);
        u64 qr = (u64)(u32)rintf(r * 16.0f);
        u64 qe = (u64)(u32)rintf(e * 16.0f);
        packed[i] = qc | (qh << 11) | (qs << 22) | (qr << 34) | (qe << 45) | (1ULL << 56);

        ah = fabsf(h); ac = fabsf(cs); ar = fabsf(r); ae = fabsf(e);
        sc = c; sh = h; sr = r;
    }
    ah = waveReduceMax(ah); ac = waveReduceMax(ac);
    ar = waveReduceMax(ar); ae = waveReduceMax(ae);
    sc = waveReduceSum(sc); sh = waveReduceSum(sh); sr = waveReduceSum(sr);

    __shared__ float red[4][7];
    int wid = threadIdx.x >> 6;
    if ((threadIdx.x & 63) == 0) {
        red[wid][0] = ah; red[wid][1] = ac; red[wid][2] = ar; red[wid][3] = ae;
        red[wid][4] = sc; red[wid][5] = sh; red[wid][6] = sr;
    }
    __syncthreads();
    if (threadIdx.x == 0) {
        float* p = partials + (size_t)blockIdx.x * 8;
        p[0] = fmaxf(fmaxf(red[0][0], red[1][0]), fmaxf(red[2][0], red[3][0]));
        p[1] = fmaxf(fmaxf(red[0][1], red[1][1]), fmaxf(red[2][1], red[3][1]));
        p[2] = fmaxf(fmaxf(red[0][2], red[1][2]), fmaxf(red[2][2], red[3][2]));
        p[3] = fmaxf(fmaxf(red[0][3], red[1][3]), fmaxf(red[2][3], red[3][3]));
        p[4] = red[0][4] + red[1][4] + red[2][4] + red[3][4];
        p[5] = red[0][5] + red[1][5] + red[2][5] + red[3][5];
        p[6] = red[0][6] + red[1][6] + red[2][6] + red[3][6];
    }
}

__global__ __launch_bounds__(256) void k1b_reduce(
    const float* __restrict__ partials, float* __restrict__ accum, int nblocks)
{
    float mh = 0.f, mc = 0.f, mr = 0.f, me = 0.f, sc = 0.f, sh = 0.f, sr = 0.f;
    for (int b = threadIdx.x; b < nblocks; b += 256) {
        const float* p = partials + (size_t)b * 8;
        mh = fmaxf(mh, p[0]); mc = fmaxf(mc, p[1]);
        mr = fmaxf(mr, p[2]); me = fmaxf(me, p[3]);
        sc += p[4]; sh += p[5]; sr += p[6];
    }
    mh = waveReduceMax(mh); mc = waveReduceMax(mc);
    mr = waveReduceMax(mr); me = waveReduceMax(me);
    sc = waveReduceSum(sc); sh = waveReduceSum(sh); sr = waveReduceSum(sr);
    __shared__ float red[4][7];
    int wid = threadIdx.x >> 6;
    if ((threadIdx.x & 63) == 0) {
        red[wid][0] = mh; red[wid][1] = mc; red[wid][2] = mr; red[wid][3] = me;
        red[wid][4] = sc; red[wid][5] = sh; red[wid][6] = sr;
    }
    __syncthreads();
    if (threadIdx.x == 0) {
        accum[0] = fmaxf(fmaxf(red[0][0], red[1][0]), fmaxf(red[2][0], red[3][0]));
        accum[1] = fmaxf(fmaxf(red[0][1], red[1][1]), fmaxf(red[2][1], red[3][1]));
        accum[2] = fmaxf(fmaxf(red[0][2], red[1][2]), fmaxf(red[2][2], red[3][2]));
        accum[3] = fmaxf(fmaxf(red[0][3], red[1][3]), fmaxf(red[2][3], red[3][3]));
        accum[4] = red[0][4] + red[1][4] + red[2][4] + red[3][4];
        accum[5] = red[0][5] + red[1][5] + red[2][5] + red[3][5];
        accum[6] = red[0][6] + red[1][6] + red[2][6] + red[3][6];
    }
}

// ---- Phase A: block-level counting sort -> coalesced bucket runs ---------
// records[b*cap + slot] = (src << 12) | (dst & 4095),  bucket b = dst >> 12
__global__ __launch_bounds__(256) void k2a_sort(
    const int* __restrict__ src, const int* __restrict__ dst,
    u32* __restrict__ records, u32* __restrict__ bucketPos,
    int E, int nb, int cap)
{
    __shared__ u32 hist[128];
    __shared__ u32 hoff[128];
    __shared__ u32 lstart[129];   // +1 sentinel
    __shared__ u32 gbase[128];
    __shared__ u32 sorted[CHUNK];          // 32 KB

    int tid = threadIdx.x;
    int e0 = blockIdx.x * CHUNK;
    int cnt = min(CHUNK, E - e0);
    if (cnt <= 0) return;
    int cnt4 = cnt >> 2;
    const int4* dst4 = (const int4*)(dst + e0);
    const int4* src4 = (const int4*)(src + e0);

    for (int i = tid; i < nb; i += 256) { hist[i] = 0; hoff[i] = 0; }
    __syncthreads();

    // pass A: histogram (int4)
    for (int i = tid; i < cnt4; i += 256) {
        int4 d = dst4[i];
        atomicAdd(&hist[d.x >> 12], 1u);
        atomicAdd(&hist[d.y >> 12], 1u);
        atomicAdd(&hist[d.z >> 12], 1u);
        atomicAdd(&hist[d.w >> 12], 1u);
    }
    for (int i = (cnt4 << 2) + tid; i < cnt; i += 256)
        atomicAdd(&hist[dst[e0 + i] >> 12], 1u);
    __syncthreads();

    // prefix scan (serial over nb) + sentinel; global reserve (padded counters)
    if (tid == 0) {
        u32 run = 0;
        for (int b = 0; b < nb; ++b) { lstart[b] = run; run += hist[b]; }
        lstart[nb] = run;   // == cnt
    }
    __syncthreads();
    for (int b = tid; b < nb; b += 256)
        gbase[b] = atomicAdd(&bucketPos[b * BP_STRIDE], hist[b]);
    __syncthreads();

    // pass B: scatter into LDS (sorted, bucket-ordered)
    for (int i = tid; i < cnt4; i += 256) {
        int4 d = dst4[i];
        int4 s = src4[i];
        {
            u32 b = (u32)d.x >> 12;
            u32 ls = lstart[b] + atomicAdd(&hoff[b], 1u);
            sorted[ls] = ((u32)s.x << 12) | ((u32)d.x & 4095u);
        }
        {
            u32 b = (u32)d.y >> 12;
            u32 ls = lstart[b] + atomicAdd(&hoff[b], 1u);
            sorted[ls] = ((u32)s.y << 12) | ((u32)d.y & 4095u);
        }
        {
            u32 b = (u32)d.z >> 12;
            u32 ls = lstart[b] + atomicAdd(&hoff[b], 1u);
            sorted[ls] = ((u32)s.z << 12) | ((u32)d.z & 4095u);
        }
        {
            u32 b = (u32)d.w >> 12;
            u32 ls = lstart[b] + atomicAdd(&hoff[b], 1u);
            sorted[ls] = ((u32)s.w << 12) | ((u32)d.w & 4095u);
        }
    }
    for (int i = (cnt4 << 2) + tid; i < cnt; i += 256) {
        int d = dst[e0 + i];
        u32 b = (u32)d >> 12;
        u32 ls = lstart[b] + atomicAdd(&hoff[b], 1u);
        sorted[ls] = ((u32)src[e0 + i] << 12) | ((u32)d & 4095u);
    }
    __syncthreads();

    // pass C: per-wave bucket-run copy (coalesced, no per-record lookup)
    int wid = tid >> 6;
    int lane = tid & 63;
    for (int b = wid; b < nb; b += 4) {
        u32 s0 = lstart[b];
        u32 s1 = lstart[b + 1];
        u32 gb = gbase[b];
        u32* dstrec = records + (size_t)b * cap;
        for (u32 i = s0 + lane; i < s1; i += 64) {
            u32 pos = gb + (i - s0);
            if (pos < (u32)cap) dstrec[pos] = sorted[i];
        }
    }
}

// ---- Phase B: one 1024-thread block per bucket, single S2 output ---------
__global__ __launch_bounds__(1024) void k2b_accum(
    const u32* __restrict__ records, const u32* __restrict__ bucketPos,
    const u64* __restrict__ packed, u64* __restrict__ S2,
    int n, int cap)
{
    __shared__ u64 acc[4096];   // 32 KB
    int bucket = blockIdx.x;
    int nodeBase = bucket << 12;
    int nNodes = min(4096, n - nodeBase);
    for (int i = threadIdx.x; i < 4096; i += 1024) acc[i] = 0;
    __syncthreads();
    u32 cnt = bucketPos[bucket * BP_STRIDE];
    if (cnt > (u32)cap) cnt = (u32)cap;
    const u32* rec = records + (size_t)bucket * cap;
    u32 r = threadIdx.x;
    for (; r + 3072 < cnt; r += 4096) {
        u32 v0 = rec[r];
        u32 v1 = rec[r + 1024];
        u32 v2 = rec[r + 2048];
        u32 v3 = rec[r + 3072];
        u64 p0 = packed[v0 >> 12];
        u64 p1 = packed[v1 >> 12];
        u64 p2 = packed[v2 >> 12];
        u64 p3 = packed[v3 >> 12];
        atomicAdd(&acc[v0 & 4095u], p0);
        atomicAdd(&acc[v1 & 4095u], p1);
        atomicAdd(&acc[v2 & 4095u], p2);
        atomicAdd(&acc[v3 & 4095u], p3);
    }
    for (; r < cnt; r += 1024) {
        u32 v = rec[r];
        atomicAdd(&acc[v & 4095u], packed[v >> 12]);
    }
    __syncthreads();
    u64* dstp = S2 + nodeBase;
    for (int i = threadIdx.x; i < nNodes; i += 1024) dstp[i] = acc[i];
}

// ---- K3: actor MLP, fp8 MFMA layer-3, 40KB LDS ---------------------------
__global__ __launch_bounds__(256, 4) void k3_mlp(
    const float4* __restrict__ featA, const float* __restrict__ ct,
    const u64* __restrict__ S2rep, int nsl, const int* __restrict__ nid,
    const int* __restrict__ currp,
    const float* __restrict__ aW2, const float* __restrict__ ab2,
    const float* __restrict__ aW3, const float* __restrict__ ab3,
    const float* __restrict__ aW4, const float* __restrict__ ab4,
    const float* __restrict__ accum, float* __restrict__ partials2,
    float* __restrict__ out, int n)
{
    __shared__ char w3t8[8192];    // fp8 W3t[col 64][j 128], 16B-XOR-swz by col&7
    __shared__ char hb8[32768];    // fp8 h[node 256][j 128], 16B-XOR-swz by row&7

    int tid  = threadIdx.x;
    int lane = tid & 63;
    int wid  = tid >> 6;
    int lc   = lane & 15;
    int lg   = lane >> 4;

    // ---- stage W3 transposed -> fp8, swizzled ----
    for (int t = tid; t < 2048; t += 256) {
        int col = t & 63;
        int j0  = (t >> 6) << 2;     // 0,4,...,124
        float w0 = aW3[(j0 + 0) * 64 + col];
        float w1 = aW3[(j0 + 1) * 64 + col];
        float w2 = aW3[(j0 + 2) * 64 + col];
        float w3 = aW3[(j0 + 3) * 64 + col];
        u32 pk = (u32)__builtin_amdgcn_cvt_pk_fp8_f32(w0, w1, 0, false);
        pk = (u32)__builtin_amdgcn_cvt_pk_fp8_f32(w2, w3, (int)pk, true);
        *(u32*)(w3t8 + col * 128 + (j0 ^ ((col & 7) << 4))) = pk;
    }

    int i0 = blockIdx.x * 256 + tid;
    int i = i0 < n ? i0 : n - 1;           // clamp: no divergence in compute
    bool valid = i0 < n;

    float inv_mh = 1.0f / fmaxf(accum[0], 1e-12f);
    float inv_mc = 1.0f / fmaxf(accum[1], 1e-12f);
    float inv_mr = 1.0f / fmaxf(accum[2], 1e-12f);
    float inv_me = 1.0f / fmaxf(accum[3], 1e-12f);
    int curr = currp[0];

    float4 f = featA[i];
    float c = ct[i];
    u64 P = 0;
    for (int s = 0; s < nsl; ++s) P += S2rep[(size_t)s * n + i];
    u32 qct = (u32)(P         & 0x7FFULL);
    u32 qh  = (u32)((P >> 11) & 0x7FFULL);
    u32 qcs = (u32)((P >> 22) & 0xFFFULL);
    u32 qr  = (u32)((P >> 34) & 0x7FFULL);
    u32 qe  = (u32)((P >> 45) & 0x7FFULL);
    u32 deg = (u32)(P >> 56);
    float icd = deg ? 1.0f / (16.0f * (float)deg) : 0.f;
    float x0 = (float)qct * icd;
    float x1 = (float)qh  * icd * inv_mh;
    float x2 = deg ? ((float)qcs * icd - 1.0f) * inv_mc : 0.f;
    float x3 = (float)qr  * icd * inv_mr;
    float x4 = (float)qe  * icd * inv_me;
    float f0 = c * (1.0f/1440.0f);
    float f1 = f.x * inv_mh, f2 = f.y * inv_mc, f3 = f.z * inv_mr, f4 = f.w * inv_me;
    float g0 = 0.5f*(f0+x0), g1 = 0.5f*(f1+x1), g2 = 0.5f*(f2+x2),
          g3 = 0.5f*(f3+x3), g4 = 0.5f*(f4+x4);

    // ---- phase 1: layer 2 (5->128) + sigmoid -> fp8 -> hb8 ----
    {
        int rowbase = tid * 128;
        int swz = (tid & 7) << 4;
        for (int j = 0; j < 128; j += 16) {
            float hv[16];
#pragma unroll
            for (int jj = 0; jj < 16; ++jj) {
                float t = ab2[j + jj];
                t = fmaf(g0, aW2[j + jj],       t);
                t = fmaf(g1, aW2[128 + j + jj], t);
                t = fmaf(g2, aW2[256 + j + jj], t);
                t = fmaf(g3, aW2[384 + j + jj], t);
                t = fmaf(g4, aW2[512 + j + jj], t);
                float e = __expf(-t);
                hv[jj] = __builtin_amdgcn_rcpf(1.0f + e);
            }
            int4 w;
            u32 a;
            a = (u32)__builtin_amdgcn_cvt_pk_fp8_f32(hv[0],  hv[1],  0, false);
            a = (u32)__builtin_amdgcn_cvt_pk_fp8_f32(hv[2],  hv[3],  (int)a, true);
            w.x = (int)a;
            a = (u32)__builtin_amdgcn_cvt_pk_fp8_f32(hv[4],  hv[5],  0, false);
            a = (u32)__builtin_amdgcn_cvt_pk_fp8_f32(hv[6],  hv[7],  (int)a, true);
            w.y = (int)a;
            a = (u32)__builtin_amdgcn_cvt_pk_fp8_f32(hv[8],  hv[9],  0, false);
            a = (u32)__builtin_amdgcn_cvt_pk_fp8_f32(hv[10], hv[11], (int)a, true);
            w.z = (int)a;
            a = (u32)__builtin_amdgcn_cvt_pk_fp8_f32(hv[12], hv[13], 0, false);
            a = (u32)__builtin_amdgcn_cvt_pk_fp8_f32(hv[14], hv[15], (int)a, true);
            w.w = (int)a;
            *(int4*)(hb8 + rowbase + (j ^ swz)) = w;
        }
    }
    __syncthreads();

    // ---- phase 2: layer 3 (128->64) via fp8 MFMA + layer 4 ----
    i64t bfr[4][4];
#pragma unroll
    for (int nt = 0; nt < 4; ++nt) {
#pragma unroll
        for (int kc = 0; kc < 4; ++kc) {
            int col = nt * 16 + lc;
            int boff = col * 128 + ((kc * 32 + lg * 8) ^ ((col & 7) << 4));
            bfr[nt][kc] = *(const i64t*)(w3t8 + boff);
        }
    }
    float b3v[4], w4v[4];
#pragma unroll
    for (int nt = 0; nt < 4; ++nt) {
        b3v[nt] = ab3[nt * 16 + lc];
        w4v[nt] = aW4[nt * 16 + lc];
    }
    float bias4 = ab4[0];

    int waveSlot = wid * 64;
    float evloc = 0.f;
#pragma unroll
    for (int mt = 0; mt < 4; ++mt) {
        i64t afr[4];
#pragma unroll
        for (int kc = 0; kc < 4; ++kc) {
            int row = waveSlot + mt * 16 + lc;
            int aoff = row * 128 + ((kc * 32 + lg * 8) ^ ((row & 7) << 4));
            afr[kc] = *(const i64t*)(hb8 + aoff);
        }
        float ps0 = 0.f, ps1 = 0.f, ps2 = 0.f, ps3 = 0.f;
#pragma unroll
        for (int nt = 0; nt < 4; ++nt) {
            f32x4 d = {0.f, 0.f, 0.f, 0.f};
            d = __builtin_amdgcn_mfma_f32_16x16x32_fp8_fp8(afr[0], bfr[nt][0], d, 0, 0, 0);
            d = __builtin_amdgcn_mfma_f32_16x16x32_fp8_fp8(afr[1], bfr[nt][1], d, 0, 0, 0);
            d = __builtin_amdgcn_mfma_f32_16x16x32_fp8_fp8(afr[2], bfr[nt][2], d, 0, 0, 0);
            d = __builtin_amdgcn_mfma_f32_16x16x32_fp8_fp8(afr[3], bfr[nt][3], d, 0, 0, 0);
            float b3 = b3v[nt], w4 = w4v[nt];
            ps0 = fmaf(sigf(d[0] + b3), w4, ps0);
            ps1 = fmaf(sigf(d[1] + b3), w4, ps1);
            ps2 = fmaf(sigf(d[2] + b3), w4, ps2);
            ps3 = fmaf(sigf(d[3] + b3), w4, ps3);
        }
#pragma unroll
        for (int off = 1; off < 16; off <<= 1) {
            ps0 += __shfl_xor(ps0, off, 64);
            ps1 += __shfl_xor(ps1, off, 64);
            ps2 += __shfl_xor(ps2, off, 64);
            ps3 += __shfl_xor(ps3, off, 64);
        }
        if (lc < 4) {
            float pv = (lc == 0) ? ps0 : (lc == 1) ? ps1 : (lc == 2) ? ps2 : ps3;
            pv += bias4;
            int slot = waveSlot + mt * 16 + lg * 4 + lc;   // D row = lg*4 + reg
            int gi = blockIdx.x * 256 + slot;
            if (gi < n) {
                float evv = (nid[gi] == curr) ? 0.f : __expf(pv);
                out[gi] = evv;
                evloc += evv;
            }
        }
    }

    float r0s = valid ? x0 : 0.f;
    float r1s = valid ? x1 : 0.f;
    float r3s = valid ? x3 : 0.f;

    float ev = waveReduceSum(evloc);
    r0s = waveReduceSum(r0s);
    r1s = waveReduceSum(r1s);
    r3s = waveReduceSum(r3s);

    __syncthreads();   // all hb8 reads done -> safe to reuse as red[]
    float (*red)[4] = (float(*)[4])hb8;
    if ((tid & 63) == 0) {
        red[wid][0] = ev; red[wid][1] = r0s; red[wid][2] = r1s; red[wid][3] = r3s;
    }
    __syncthreads();
    if (tid == 0) {
        float* p2 = partials2 + (size_t)blockIdx.x * 4;
        p2[0] = red[0][0] + red[1][0] + red[2][0] + red[3][0];
        p2[1] = red[0][1] + red[1][1] + red[2][1] + red[3][1];
        p2[2] = red[0][2] + red[1][2] + red[2][2] + red[3][2];
        p2[3] = red[0][3] + red[1][3] + red[2][3] + red[3][3];
    }
}

__global__ __launch_bounds__(256) void k3b_reduce(
    const float* __restrict__ partials2, float* __restrict__ accum, int nblocks)
{
    float s0 = 0.f, s1 = 0.f, s2 = 0.f, s3 = 0.f;
    for (int b = threadIdx.x; b < nblocks; b += 256) {
        const float* p = partials2 + (size_t)b * 4;
        s0 += p[0]; s1 += p[1]; s2 += p[2]; s3 += p[3];
    }
    s0 = waveReduceSum(s0); s1 = waveReduceSum(s1);
    s2 = waveReduceSum(s2); s3 = waveReduceSum(s3);
    __shared__ float red[4][4];
    int wid = threadIdx.x >> 6;
    if ((threadIdx.x & 63) == 0) {
        red[wid][0] = s0; red[wid][1] = s1; red[wid][2] = s2; red[wid][3] = s3;
    }
    __syncthreads();
    if (threadIdx.x == 0) {
        accum[7]  = red[0][0] + red[1][0] + red[2][0] + red[3][0];
        accum[8]  = red[0][1] + red[1][1] + red[2][1] + red[3][1];
        accum[9]  = red[0][2] + red[1][2] + red[2][2] + red[3][2];
        accum[10] = red[0][3] + red[1][3] + red[2][3] + red[3][3];
    }
}

__global__ void k4_critic(const float* __restrict__ accum,
                          const float* __restrict__ cW2, const float* __restrict__ cb2,
                          const float* __restrict__ cW3, const float* __restrict__ cb3,
                          const float* __restrict__ cW4, const float* __restrict__ cb4,
                          float* __restrict__ out, int n)
{
    __shared__ float v1[128];
    __shared__ float v2[64];
    int t = threadIdx.x;
    float invN = 1.0f / (float)n;
    float inv_mh = 1.0f / fmaxf(accum[0], 1e-12f);
    float inv_mr = 1.0f / fmaxf(accum[2], 1e-12f);
    float cx0 = accum[4] * invN * (1.0f / 1440.0f);
    float cx1 = accum[5] * invN * inv_mh;
    float cx2 = accum[6] * invN * inv_mr;
    float cx3 = accum[8] * invN;
    float cx4 = accum[9] * invN;
    float cx5 = accum[10] * invN;
    if (t < 128) {
        float a = cb2[t];
        a = fmaf(cx0, cW2[t],       a);
        a = fmaf(cx1, cW2[128 + t], a);
        a = fmaf(cx2, cW2[256 + t], a);
        a = fmaf(cx3, cW2[384 + t], a);
        a = fmaf(cx4, cW2[512 + t], a);
        a = fmaf(cx5, cW2[640 + t], a);
        v1[t] = sigf(a);
    }
    __syncthreads();
    if (t < 64) {
        float a = cb3[t];
        for (int j = 0; j < 128; ++j) a = fmaf(v1[j], cW3[j * 64 + t], a);
        v2[t] = sigf(a);
    }
    __syncthreads();
    if (t == 0) {
        float a = cb4[0];
        for (int k = 0; k < 64; ++k) a = fmaf(v2[k], cW4[k], a);
        out[n] = a;  // value
    }
}

__global__ void k5_scale(float* __restrict__ out, const float* __restrict__ accum, int n)
{
    int i = blockIdx.x * blockDim.x + threadIdx.x;
    float inv = 1.0f / accum[7];
    if (i < n) out[i] *= inv;
}

// fallback: one global u64 atomic per edge
__global__ void k2_atomic(const int* __restrict__ src, const int* __restrict__ dst,
                          const u64* __restrict__ packed, u64* __restrict__ S2, int E)
{
    int stride = gridDim.x * blockDim.x;
    for (int e = blockIdx.x * blockDim.x + threadIdx.x; e < E; e += stride) {
        atomicAdd(S2 + dst[e], packed[src[e]]);
    }
}

extern "C" void kernel_launch(void* const* d_in, const int* in_sizes, int n_in,
                              void* d_out, int out_size, void* d_ws, size_t ws_size,
                              hipStream_t stream)
{
    const float* hop = (const float*)d_in[0];
    const float* rd  = (const float*)d_in[1];
    const float* ett = (const float*)d_in[2];
    const float* ct  = (const float*)d_in[3];
    const float* c2n = (const float*)d_in[4];
    const float* c2t = (const float*)d_in[5];
    const int*   nid = (const int*)d_in[6];
    const int*   src = (const int*)d_in[7];
    const int*   dst = (const int*)d_in[8];
    const int*   cur = (const int*)d_in[9];
    const float* aW2 = (const float*)d_in[10];
    const float* ab2 = (const float*)d_in[11];
    const float* aW3 = (const float*)d_in[12];
    const float* ab3 = (const float*)d_in[13];
    const float* aW4 = (const float*)d_in[14];
    const float* ab4 = (const float*)d_in[15];
    const float* cW2 = (const float*)d_in[16];
    const float* cb2 = (const float*)d_in[17];
    const float* cW3 = (const float*)d_in[18];
    const float* cb3 = (const float*)d_in[19];
    const float* cW4 = (const float*)d_in[20];
    const float* cb4 = (const float*)d_in[21];

    int n = in_sizes[0];
    int E = in_sizes[7];
    float* out = (float*)d_out;

    int nb  = (n + 4095) >> 12;                       // buckets of 4096 nodes
    int cap = E / (nb > 0 ? nb : 1) + 8192;           // >22 sigma slack
    int nbk = (n + 255) / 256;

    char* ws = (char*)d_ws;
    float4* featA  = (float4*)ws;                     // 16n
    u64*    packed = (u64*)(ws + (size_t)16 * n);     // 8n
    u64*    S2     = (u64*)(ws + (size_t)24 * n);     // 8n (single array now)

    size_t tail_bucket = (size_t)56 * n;   // layout kept from r16 for safety
    size_t tail_fb     = (size_t)32 * n;
    size_t tailsz = 256 + 8192 + (size_t)48 * nbk;
    size_t needed = tail_bucket + tailsz + (size_t)nb * cap * 4;
    bool bucketPath = (ws_size >= needed) && (nb <= 128);

    char* base = ws + (bucketPath ? tail_bucket : tail_fb);
    float* accum     = (float*)base;                              // 256 B
    u32*   bucketPos = (u32*)(base + 256);                        // 8192 B padded
    float* partials  = (float*)(base + 256 + 8192);               // 32*nbk B
    float* partials2 = (float*)(base + 256 + 8192 + (size_t)32 * nbk); // 16*nbk B
    u32*   records   = (u32*)(base + tailsz);

    if (bucketPath) {
        hipMemsetAsync(bucketPos, 0, 8192, stream);
        k1_prep<<<nbk, 256, 0, stream>>>(hop, rd, ett, ct, c2n, c2t, featA, packed, partials, n);
        k1b_reduce<<<1, 256, 0, stream>>>(partials, accum, nbk);
        int nchunks = (E + CHUNK - 1) / CHUNK;
        k2a_sort<<<nchunks, 256, 0, stream>>>(src, dst, records, bucketPos, E, nb, cap);
        k2b_accum<<<nb, 1024, 0, stream>>>(records, bucketPos, packed, S2, n, cap);
        k3_mlp<<<nbk, 256, 0, stream>>>(featA, ct, S2, 1, nid, cur,
                                        aW2, ab2, aW3, ab3, aW4, ab4, accum, partials2, out, n);
        k3b_reduce<<<1, 256, 0, stream>>>(partials2, accum, nbk);
    } else {
        u64* S2f = (u64*)(ws + (size_t)24 * n);
        hipMemsetAsync(S2f, 0, (size_t)8 * n, stream);
        k1_prep<<<nbk, 256, 0, stream>>>(hop, rd, ett, ct, c2n, c2t, featA, packed, partials, n);
        k1b_reduce<<<1, 256, 0, stream>>>(partials, accum, nbk);
        k2_atomic<<<4096, 256, 0, stream>>>(src, dst, packed, S2f, E);
        k3_mlp<<<nbk, 256, 0, stream>>>(featA, ct, S2f, 1, nid, cur,
                                        aW2, ab2, aW3, ab3, aW4, ab4, accum, partials2, out, n);
        k3b_reduce<<<1, 256, 0, stream>>>(partials2, accum, nbk);
    }
    k4_critic<<<1, 128, 0, stream>>>(accum, cW2, cb2, cW3, cb3, cW4, cb4, out, n);
    k5_scale<<<nbk, 256, 0, stream>>>(out, accum, n);
}

// Round 21
// 264.931 us; speedup vs baseline: 1.2294x; 1.2294x over previous
//
#include <hip/hip_runtime.h>
#include <hip/hip_bf16.h>

// ---------------------------------------------------------------------------
// PPO Actor-Critic GNN on MI355X.
// Round 21: r20's one-block-per-bucket k2b starved the chip (123 blocks,
// 20% occ, 159us). Revert to sliced k2b (256-thr blocks) and RAISE
// parallelism: NSL=8 slices -> 984 blocks (~3.8/CU, 4 co-resident via 32KB
// acc) + 8-way unrolled gather chains. Replica traffic +32MB ~= 5us, noise.
// k2a = counting-sort scatter (r18); k3 = fp8 MFMA (r16); scalar reductions
// via partials (no same-line global atomics, r10/11).
// ---------------------------------------------------------------------------

typedef unsigned int u32;
typedef unsigned long long u64;
typedef long long i64t;
typedef __attribute__((ext_vector_type(4))) float f32x4;

#define BP_STRIDE 16   // bucketPos padding: 16 u32 = 64B per counter
#define CHUNK 8192

__device__ __forceinline__ float sigf(float x) { return 1.0f / (1.0f + __expf(-x)); }

__device__ __forceinline__ float waveReduceSum(float v) {
#pragma unroll
    for (int off = 32; off > 0; off >>= 1) v += __shfl_down(v, off, 64);
    return v;
}
__device__ __forceinline__ float waveReduceMax(float v) {
#pragma unroll
    for (int off = 32; off > 0; off >>= 1) v = fmaxf(v, __shfl_down(v, off, 64));
    return v;
}

// accum layout (floats):
// [0] max|hop| [1] max|cos| [2] max|rd| [3] max|ett|
// [4] sum ct   [5] sum hop  [6] sum rd
// [7] sum exp(policy)
// [8] sum x_ct  [9] sum x_hop_norm  [10] sum x_rd_norm

__global__ __launch_bounds__(256) void k1_prep(
    const float* __restrict__ hop, const float* __restrict__ rd,
    const float* __restrict__ ett, const float* __restrict__ ct,
    const float* __restrict__ c2n, const float* __restrict__ c2t,
    float4* __restrict__ featA, u64* __restrict__ packed,
    float* __restrict__ partials, int n)
{
    int i = blockIdx.x * blockDim.x + threadIdx.x;
    float ah = 0.f, ac = 0.f, ar = 0.f, ae = 0.f, sc = 0.f, sh = 0.f, sr = 0.f;
    if (i < n) {
        float h = hop[i], r = rd[i], e = ett[i], c = ct[i];
        float ax = c2n[3*i+0], ay = c2n[3*i+1], az = c2n[3*i+2];
        float bx = c2t[3*i+0], by = c2t[3*i+1], bz = c2t[3*i+2];
        float dot = ax*bx + ay*by + az*bz;
        float na = fmaxf(sqrtf(ax*ax + ay*ay + az*az), 1e-6f);
        float nb = fmaxf(sqrtf(bx*bx + by*by + bz*bz), 1e-6f);
        float cs = dot / (na * nb);
        featA[i] = make_float4(h, cs, r, e);

        // single-u64 fixed-point pack, scale 16
        // fields: ct 11b | hop 11b | cos+1 12b | rd 11b | ett 11b | deg 8b
        u64 qc = (u64)(u32)rintf(c * (16.0f/1440.0f));
        u64 qh = (u64)(u32)rintf(h * 16.0f);
        u64 qs = (u64)(u32)rintf((cs + 1.0f) * 16.0f);
        u64 qr = (u64)(u32)rintf(r * 16.0f);
        u64 qe = (u64)(u32)rintf(e * 16.0f);
        packed[i] = qc | (qh << 11) | (qs << 22) | (qr << 34) | (qe << 45) | (1ULL << 56);

        ah = fabsf(h); ac = fabsf(cs); ar = fabsf(r); ae = fabsf(e);
        sc = c; sh = h; sr = r;
    }
    ah = waveReduceMax(ah); ac = waveReduceMax(ac);
    ar = waveReduceMax(ar); ae = waveReduceMax(ae);
    sc = waveReduceSum(sc); sh = waveReduceSum(sh); sr = waveReduceSum(sr);

    __shared__ float red[4][7];
    int wid = threadIdx.x >> 6;
    if ((threadIdx.x & 63) == 0) {
        red[wid][0] = ah; red[wid][1] = ac; red[wid][2] = ar; red[wid][3] = ae;
        red[wid][4] = sc; red[wid][5] = sh; red[wid][6] = sr;
    }
    __syncthreads();
    if (threadIdx.x == 0) {
        float* p = partials + (size_t)blockIdx.x * 8;
        p[0] = fmaxf(fmaxf(red[0][0], red[1][0]), fmaxf(red[2][0], red[3][0]));
        p[1] = fmaxf(fmaxf(red[0][1], red[1][1]), fmaxf(red[2][1], red[3][1]));
        p[2] = fmaxf(fmaxf(red[0][2], red[1][2]), fmaxf(red[2][2], red[3][2]));
        p[3] = fmaxf(fmaxf(red[0][3], red[1][3]), fmaxf(red[2][3], red[3][3]));
        p[4] = red[0][4] + red[1][4] + red[2][4] + red[3][4];
        p[5] = red[0][5] + red[1][5] + red[2][5] + red[3][5];
        p[6] = red[0][6] + red[1][6] + red[2][6] + red[3][6];
    }
}

__global__ __launch_bounds__(256) void k1b_reduce(
    const float* __restrict__ partials, float* __restrict__ accum, int nblocks)
{
    float mh = 0.f, mc = 0.f, mr = 0.f, me = 0.f, sc = 0.f, sh = 0.f, sr = 0.f;
    for (int b = threadIdx.x; b < nblocks; b += 256) {
        const float* p = partials + (size_t)b * 8;
        mh = fmaxf(mh, p[0]); mc = fmaxf(mc, p[1]);
        mr = fmaxf(mr, p[2]); me = fmaxf(me, p[3]);
        sc += p[4]; sh += p[5]; sr += p[6];
    }
    mh = waveReduceMax(mh); mc = waveReduceMax(mc);
    mr = waveReduceMax(mr); me = waveReduceMax(me);
    sc = waveReduceSum(sc); sh = waveReduceSum(sh); sr = waveReduceSum(sr);
    __shared__ float red[4][7];
    int wid = threadIdx.x >> 6;
    if ((threadIdx.x & 63) == 0) {
        red[wid][0] = mh; red[wid][1] = mc; red[wid][2] = mr; red[wid][3] = me;
        red[wid][4] = sc; red[wid][5] = sh; red[wid][6] = sr;
    }
    __syncthreads();
    if (threadIdx.x == 0) {
        accum[0] = fmaxf(fmaxf(red[0][0], red[1][0]), fmaxf(red[2][0], red[3][0]));
        accum[1] = fmaxf(fmaxf(red[0][1], red[1][1]), fmaxf(red[2][1], red[3][1]));
        accum[2] = fmaxf(fmaxf(red[0][2], red[1][2]), fmaxf(red[2][2], red[3][2]));
        accum[3] = fmaxf(fmaxf(red[0][3], red[1][3]), fmaxf(red[2][3], red[3][3]));
        accum[4] = red[0][4] + red[1][4] + red[2][4] + red[3][4];
        accum[5] = red[0][5] + red[1][5] + red[2][5] + red[3][5];
        accum[6] = red[0][6] + red[1][6] + red[2][6] + red[3][6];
    }
}

// ---- Phase A: block-level counting sort -> coalesced bucket runs ---------
// records[b*cap + slot] = (src << 12) | (dst & 4095),  bucket b = dst >> 12
__global__ __launch_bounds__(256) void k2a_sort(
    const int* __restrict__ src, const int* __restrict__ dst,
    u32* __restrict__ records, u32* __restrict__ bucketPos,
    int E, int nb, int cap)
{
    __shared__ u32 hist[128];
    __shared__ u32 hoff[128];
    __shared__ u32 lstart[129];   // +1 sentinel
    __shared__ u32 gbase[128];
    __shared__ u32 sorted[CHUNK];          // 32 KB

    int tid = threadIdx.x;
    int e0 = blockIdx.x * CHUNK;
    int cnt = min(CHUNK, E - e0);
    if (cnt <= 0) return;
    int cnt4 = cnt >> 2;
    const int4* dst4 = (const int4*)(dst + e0);
    const int4* src4 = (const int4*)(src + e0);

    for (int i = tid; i < nb; i += 256) { hist[i] = 0; hoff[i] = 0; }
    __syncthreads();

    // pass A: histogram (int4)
    for (int i = tid; i < cnt4; i += 256) {
        int4 d = dst4[i];
        atomicAdd(&hist[d.x >> 12], 1u);
        atomicAdd(&hist[d.y >> 12], 1u);
        atomicAdd(&hist[d.z >> 12], 1u);
        atomicAdd(&hist[d.w >> 12], 1u);
    }
    for (int i = (cnt4 << 2) + tid; i < cnt; i += 256)
        atomicAdd(&hist[dst[e0 + i] >> 12], 1u);
    __syncthreads();

    // prefix scan (serial over nb) + sentinel; global reserve (padded counters)
    if (tid == 0) {
        u32 run = 0;
        for (int b = 0; b < nb; ++b) { lstart[b] = run; run += hist[b]; }
        lstart[nb] = run;   // == cnt
    }
    __syncthreads();
    for (int b = tid; b < nb; b += 256)
        gbase[b] = atomicAdd(&bucketPos[b * BP_STRIDE], hist[b]);
    __syncthreads();

    // pass B: scatter into LDS (sorted, bucket-ordered)
    for (int i = tid; i < cnt4; i += 256) {
        int4 d = dst4[i];
        int4 s = src4[i];
        {
            u32 b = (u32)d.x >> 12;
            u32 ls = lstart[b] + atomicAdd(&hoff[b], 1u);
            sorted[ls] = ((u32)s.x << 12) | ((u32)d.x & 4095u);
        }
        {
            u32 b = (u32)d.y >> 12;
            u32 ls = lstart[b] + atomicAdd(&hoff[b], 1u);
            sorted[ls] = ((u32)s.y << 12) | ((u32)d.y & 4095u);
        }
        {
            u32 b = (u32)d.z >> 12;
            u32 ls = lstart[b] + atomicAdd(&hoff[b], 1u);
            sorted[ls] = ((u32)s.z << 12) | ((u32)d.z & 4095u);
        }
        {
            u32 b = (u32)d.w >> 12;
            u32 ls = lstart[b] + atomicAdd(&hoff[b], 1u);
            sorted[ls] = ((u32)s.w << 12) | ((u32)d.w & 4095u);
        }
    }
    for (int i = (cnt4 << 2) + tid; i < cnt; i += 256) {
        int d = dst[e0 + i];
        u32 b = (u32)d >> 12;
        u32 ls = lstart[b] + atomicAdd(&hoff[b], 1u);
        sorted[ls] = ((u32)src[e0 + i] << 12) | ((u32)d & 4095u);
    }
    __syncthreads();

    // pass C: per-wave bucket-run copy (coalesced, no per-record lookup)
    int wid = tid >> 6;
    int lane = tid & 63;
    for (int b = wid; b < nb; b += 4) {
        u32 s0 = lstart[b];
        u32 s1 = lstart[b + 1];
        u32 gb = gbase[b];
        u32* dstrec = records + (size_t)b * cap;
        for (u32 i = s0 + lane; i < s1; i += 64) {
            u32 pos = gb + (i - s0);
            if (pos < (u32)cap) dstrec[pos] = sorted[i];
        }
    }
}

// ---- Phase B: LDS accumulate + replica flush (bucket x slice grid) -------
__global__ __launch_bounds__(256) void k2b_accum(
    const u32* __restrict__ records, const u32* __restrict__ bucketPos,
    const u64* __restrict__ packed, u64* __restrict__ S2rep,
    int n, int cap, int nsl)
{
    __shared__ u64 acc[4096];   // 32 KB
    int bucket = blockIdx.x / nsl;
    int slice  = blockIdx.x % nsl;
    int nodeBase = bucket << 12;
    int nNodes = min(4096, n - nodeBase);
    for (int i = threadIdx.x; i < 4096; i += 256) acc[i] = 0;
    __syncthreads();
    u32 cnt = bucketPos[bucket * BP_STRIDE];
    if (cnt > (u32)cap) cnt = (u32)cap;
    u32 lo = (u32)(((u64)cnt * (u32)slice) / (u32)nsl);
    u32 hi = (u32)(((u64)cnt * (u32)(slice + 1)) / (u32)nsl);
    const u32* rec = records + (size_t)bucket * cap;
    u32 r = lo + threadIdx.x;
    // 8-way unrolled independent gather chains
    for (; r + 1792 < hi; r += 2048) {
        u32 v0 = rec[r];
        u32 v1 = rec[r + 256];
        u32 v2 = rec[r + 512];
        u32 v3 = rec[r + 768];
        u32 v4 = rec[r + 1024];
        u32 v5 = rec[r + 1280];
        u32 v6 = rec[r + 1536];
        u32 v7 = rec[r + 1792];
        u64 p0 = packed[v0 >> 12];
        u64 p1 = packed[v1 >> 12];
        u64 p2 = packed[v2 >> 12];
        u64 p3 = packed[v3 >> 12];
        u64 p4 = packed[v4 >> 12];
        u64 p5 = packed[v5 >> 12];
        u64 p6 = packed[v6 >> 12];
        u64 p7 = packed[v7 >> 12];
        atomicAdd(&acc[v0 & 4095u], p0);
        atomicAdd(&acc[v1 & 4095u], p1);
        atomicAdd(&acc[v2 & 4095u], p2);
        atomicAdd(&acc[v3 & 4095u], p3);
        atomicAdd(&acc[v4 & 4095u], p4);
        atomicAdd(&acc[v5 & 4095u], p5);
        atomicAdd(&acc[v6 & 4095u], p6);
        atomicAdd(&acc[v7 & 4095u], p7);
    }
    for (; r < hi; r += 256) {
        u32 v = rec[r];
        atomicAdd(&acc[v & 4095u], packed[v >> 12]);
    }
    __syncthreads();
    u64* dstp = S2rep + (size_t)slice * n + nodeBase;
    for (int i = threadIdx.x; i < nNodes; i += 256) dstp[i] = acc[i];
}

// ---- K3: actor MLP, fp8 MFMA layer-3, 40KB LDS ---------------------------
__global__ __launch_bounds__(256, 4) void k3_mlp(
    const float4* __restrict__ featA, const float* __restrict__ ct,
    const u64* __restrict__ S2rep, int nsl, const int* __restrict__ nid,
    const int* __restrict__ currp,
    const float* __restrict__ aW2, const float* __restrict__ ab2,
    const float* __restrict__ aW3, const float* __restrict__ ab3,
    const float* __restrict__ aW4, const float* __restrict__ ab4,
    const float* __restrict__ accum, float* __restrict__ partials2,
    float* __restrict__ out, int n)
{
    __shared__ char w3t8[8192];    // fp8 W3t[col 64][j 128], 16B-XOR-swz by col&7
    __shared__ char hb8[32768];    // fp8 h[node 256][j 128], 16B-XOR-swz by row&7

    int tid  = threadIdx.x;
    int lane = tid & 63;
    int wid  = tid >> 6;
    int lc   = lane & 15;
    int lg   = lane >> 4;

    // ---- stage W3 transposed -> fp8, swizzled ----
    for (int t = tid; t < 2048; t += 256) {
        int col = t & 63;
        int j0  = (t >> 6) << 2;     // 0,4,...,124
        float w0 = aW3[(j0 + 0) * 64 + col];
        float w1 = aW3[(j0 + 1) * 64 + col];
        float w2 = aW3[(j0 + 2) * 64 + col];
        float w3 = aW3[(j0 + 3) * 64 + col];
        u32 pk = (u32)__builtin_amdgcn_cvt_pk_fp8_f32(w0, w1, 0, false);
        pk = (u32)__builtin_amdgcn_cvt_pk_fp8_f32(w2, w3, (int)pk, true);
        *(u32*)(w3t8 + col * 128 + (j0 ^ ((col & 7) << 4))) = pk;
    }

    int i0 = blockIdx.x * 256 + tid;
    int i = i0 < n ? i0 : n - 1;           // clamp: no divergence in compute
    bool valid = i0 < n;

    float inv_mh = 1.0f / fmaxf(accum[0], 1e-12f);
    float inv_mc = 1.0f / fmaxf(accum[1], 1e-12f);
    float inv_mr = 1.0f / fmaxf(accum[2], 1e-12f);
    float inv_me = 1.0f / fmaxf(accum[3], 1e-12f);
    int curr = currp[0];

    float4 f = featA[i];
    float c = ct[i];
    u64 P = 0;
    for (int s = 0; s < nsl; ++s) P += S2rep[(size_t)s * n + i];
    u32 qct = (u32)(P         & 0x7FFULL);
    u32 qh  = (u32)((P >> 11) & 0x7FFULL);
    u32 qcs = (u32)((P >> 22) & 0xFFFULL);
    u32 qr  = (u32)((P >> 34) & 0x7FFULL);
    u32 qe  = (u32)((P >> 45) & 0x7FFULL);
    u32 deg = (u32)(P >> 56);
    float icd = deg ? 1.0f / (16.0f * (float)deg) : 0.f;
    float x0 = (float)qct * icd;
    float x1 = (float)qh  * icd * inv_mh;
    float x2 = deg ? ((float)qcs * icd - 1.0f) * inv_mc : 0.f;
    float x3 = (float)qr  * icd * inv_mr;
    float x4 = (float)qe  * icd * inv_me;
    float f0 = c * (1.0f/1440.0f);
    float f1 = f.x * inv_mh, f2 = f.y * inv_mc, f3 = f.z * inv_mr, f4 = f.w * inv_me;
    float g0 = 0.5f*(f0+x0), g1 = 0.5f*(f1+x1), g2 = 0.5f*(f2+x2),
          g3 = 0.5f*(f3+x3), g4 = 0.5f*(f4+x4);

    // ---- phase 1: layer 2 (5->128) + sigmoid -> fp8 -> hb8 ----
    {
        int rowbase = tid * 128;
        int swz = (tid & 7) << 4;
        for (int j = 0; j < 128; j += 16) {
            float hv[16];
#pragma unroll
            for (int jj = 0; jj < 16; ++jj) {
                float t = ab2[j + jj];
                t = fmaf(g0, aW2[j + jj],       t);
                t = fmaf(g1, aW2[128 + j + jj], t);
                t = fmaf(g2, aW2[256 + j + jj], t);
                t = fmaf(g3, aW2[384 + j + jj], t);
                t = fmaf(g4, aW2[512 + j + jj], t);
                float e = __expf(-t);
                hv[jj] = __builtin_amdgcn_rcpf(1.0f + e);
            }
            int4 w;
            u32 a;
            a = (u32)__builtin_amdgcn_cvt_pk_fp8_f32(hv[0],  hv[1],  0, false);
            a = (u32)__builtin_amdgcn_cvt_pk_fp8_f32(hv[2],  hv[3],  (int)a, true);
            w.x = (int)a;
            a = (u32)__builtin_amdgcn_cvt_pk_fp8_f32(hv[4],  hv[5],  0, false);
            a = (u32)__builtin_amdgcn_cvt_pk_fp8_f32(hv[6],  hv[7],  (int)a, true);
            w.y = (int)a;
            a = (u32)__builtin_amdgcn_cvt_pk_fp8_f32(hv[8],  hv[9],  0, false);
            a = (u32)__builtin_amdgcn_cvt_pk_fp8_f32(hv[10], hv[11], (int)a, true);
            w.z = (int)a;
            a = (u32)__builtin_amdgcn_cvt_pk_fp8_f32(hv[12], hv[13], 0, false);
            a = (u32)__builtin_amdgcn_cvt_pk_fp8_f32(hv[14], hv[15], (int)a, true);
            w.w = (int)a;
            *(int4*)(hb8 + rowbase + (j ^ swz)) = w;
        }
    }
    __syncthreads();

    // ---- phase 2: layer 3 (128->64) via fp8 MFMA + layer 4 ----
    i64t bfr[4][4];
#pragma unroll
    for (int nt = 0; nt < 4; ++nt) {
#pragma unroll
        for (int kc = 0; kc < 4; ++kc) {
            int col = nt * 16 + lc;
            int boff = col * 128 + ((kc * 32 + lg * 8) ^ ((col & 7) << 4));
            bfr[nt][kc] = *(const i64t*)(w3t8 + boff);
        }
    }
    float b3v[4], w4v[4];
#pragma unroll
    for (int nt = 0; nt < 4; ++nt) {
        b3v[nt] = ab3[nt * 16 + lc];
        w4v[nt] = aW4[nt * 16 + lc];
    }
    float bias4 = ab4[0];

    int waveSlot = wid * 64;
    float evloc = 0.f;
#pragma unroll
    for (int mt = 0; mt < 4; ++mt) {
        i64t afr[4];
#pragma unroll
        for (int kc = 0; kc < 4; ++kc) {
            int row = waveSlot + mt * 16 + lc;
            int aoff = row * 128 + ((kc * 32 + lg * 8) ^ ((row & 7) << 4));
            afr[kc] = *(const i64t*)(hb8 + aoff);
        }
        float ps0 = 0.f, ps1 = 0.f, ps2 = 0.f, ps3 = 0.f;
#pragma unroll
        for (int nt = 0; nt < 4; ++nt) {
            f32x4 d = {0.f, 0.f, 0.f, 0.f};
            d = __builtin_amdgcn_mfma_f32_16x16x32_fp8_fp8(afr[0], bfr[nt][0], d, 0, 0, 0);
            d = __builtin_amdgcn_mfma_f32_16x16x32_fp8_fp8(afr[1], bfr[nt][1], d, 0, 0, 0);
            d = __builtin_amdgcn_mfma_f32_16x16x32_fp8_fp8(afr[2], bfr[nt][2], d, 0, 0, 0);
            d = __builtin_amdgcn_mfma_f32_16x16x32_fp8_fp8(afr[3], bfr[nt][3], d, 0, 0, 0);
            float b3 = b3v[nt], w4 = w4v[nt];
            ps0 = fmaf(sigf(d[0] + b3), w4, ps0);
            ps1 = fmaf(sigf(d[1] + b3), w4, ps1);
            ps2 = fmaf(sigf(d[2] + b3), w4, ps2);
            ps3 = fmaf(sigf(d[3] + b3), w4, ps3);
        }
#pragma unroll
        for (int off = 1; off < 16; off <<= 1) {
            ps0 += __shfl_xor(ps0, off, 64);
            ps1 += __shfl_xor(ps1, off, 64);
            ps2 += __shfl_xor(ps2, off, 64);
            ps3 += __shfl_xor(ps3, off, 64);
        }
        if (lc < 4) {
            float pv = (lc == 0) ? ps0 : (lc == 1) ? ps1 : (lc == 2) ? ps2 : ps3;
            pv += bias4;
            int slot = waveSlot + mt * 16 + lg * 4 + lc;   // D row = lg*4 + reg
            int gi = blockIdx.x * 256 + slot;
            if (gi < n) {
                float evv = (nid[gi] == curr) ? 0.f : __expf(pv);
                out[gi] = evv;
                evloc += evv;
            }
        }
    }

    float r0s = valid ? x0 : 0.f;
    float r1s = valid ? x1 : 0.f;
    float r3s = valid ? x3 : 0.f;

    float ev = waveReduceSum(evloc);
    r0s = waveReduceSum(r0s);
    r1s = waveReduceSum(r1s);
    r3s = waveReduceSum(r3s);

    __syncthreads();   // all hb8 reads done -> safe to reuse as red[]
    float (*red)[4] = (float(*)[4])hb8;
    if ((tid & 63) == 0) {
        red[wid][0] = ev; red[wid][1] = r0s; red[wid][2] = r1s; red[wid][3] = r3s;
    }
    __syncthreads();
    if (tid == 0) {
        float* p2 = partials2 + (size_t)blockIdx.x * 4;
        p2[0] = red[0][0] + red[1][0] + red[2][0] + red[3][0];
        p2[1] = red[0][1] + red[1][1] + red[2][1] + red[3][1];
        p2[2] = red[0][2] + red[1][2] + red[2][2] + red[3][2];
        p2[3] = red[0][3] + red[1][3] + red[2][3] + red[3][3];
    }
}

__global__ __launch_bounds__(256) void k3b_reduce(
    const float* __restrict__ partials2, float* __restrict__ accum, int nblocks)
{
    float s0 = 0.f, s1 = 0.f, s2 = 0.f, s3 = 0.f;
    for (int b = threadIdx.x; b < nblocks; b += 256) {
        const float* p = partials2 + (size_t)b * 4;
        s0 += p[0]; s1 += p[1]; s2 += p[2]; s3 += p[3];
    }
    s0 = waveReduceSum(s0); s1 = waveReduceSum(s1);
    s2 = waveReduceSum(s2); s3 = waveReduceSum(s3);
    __shared__ float red[4][4];
    int wid = threadIdx.x >> 6;
    if ((threadIdx.x & 63) == 0) {
        red[wid][0] = s0; red[wid][1] = s1; red[wid][2] = s2; red[wid][3] = s3;
    }
    __syncthreads();
    if (threadIdx.x == 0) {
        accum[7]  = red[0][0] + red[1][0] + red[2][0] + red[3][0];
        accum[8]  = red[0][1] + red[1][1] + red[2][1] + red[3][1];
        accum[9]  = red[0][2] + red[1][2] + red[2][2] + red[3][2];
        accum[10] = red[0][3] + red[1][3] + red[2][3] + red[3][3];
    }
}

__global__ void k4_critic(const float* __restrict__ accum,
                          const float* __restrict__ cW2, const float* __restrict__ cb2,
                          const float* __restrict__ cW3, const float* __restrict__ cb3,
                          const float* __restrict__ cW4, const float* __restrict__ cb4,
                          float* __restrict__ out, int n)
{
    __shared__ float v1[128];
    __shared__ float v2[64];
    int t = threadIdx.x;
    float invN = 1.0f / (float)n;
    float inv_mh = 1.0f / fmaxf(accum[0], 1e-12f);
    float inv_mr = 1.0f / fmaxf(accum[2], 1e-12f);
    float cx0 = accum[4] * invN * (1.0f / 1440.0f);
    float cx1 = accum[5] * invN * inv_mh;
    float cx2 = accum[6] * invN * inv_mr;
    float cx3 = accum[8] * invN;
    float cx4 = accum[9] * invN;
    float cx5 = accum[10] * invN;
    if (t < 128) {
        float a = cb2[t];
        a = fmaf(cx0, cW2[t],       a);
        a = fmaf(cx1, cW2[128 + t], a);
        a = fmaf(cx2, cW2[256 + t], a);
        a = fmaf(cx3, cW2[384 + t], a);
        a = fmaf(cx4, cW2[512 + t], a);
        a = fmaf(cx5, cW2[640 + t], a);
        v1[t] = sigf(a);
    }
    __syncthreads();
    if (t < 64) {
        float a = cb3[t];
        for (int j = 0; j < 128; ++j) a = fmaf(v1[j], cW3[j * 64 + t], a);
        v2[t] = sigf(a);
    }
    __syncthreads();
    if (t == 0) {
        float a = cb4[0];
        for (int k = 0; k < 64; ++k) a = fmaf(v2[k], cW4[k], a);
        out[n] = a;  // value
    }
}

__global__ void k5_scale(float* __restrict__ out, const float* __restrict__ accum, int n)
{
    int i = blockIdx.x * blockDim.x + threadIdx.x;
    float inv = 1.0f / accum[7];
    if (i < n) out[i] *= inv;
}

// fallback: one global u64 atomic per edge
__global__ void k2_atomic(const int* __restrict__ src, const int* __restrict__ dst,
                          const u64* __restrict__ packed, u64* __restrict__ S2, int E)
{
    int stride = gridDim.x * blockDim.x;
    for (int e = blockIdx.x * blockDim.x + threadIdx.x; e < E; e += stride) {
        atomicAdd(S2 + dst[e], packed[src[e]]);
    }
}

extern "C" void kernel_launch(void* const* d_in, const int* in_sizes, int n_in,
                              void* d_out, int out_size, void* d_ws, size_t ws_size,
                              hipStream_t stream)
{
    const float* hop = (const float*)d_in[0];
    const float* rd  = (const float*)d_in[1];
    const float* ett = (const float*)d_in[2];
    const float* ct  = (const float*)d_in[3];
    const float* c2n = (const float*)d_in[4];
    const float* c2t = (const float*)d_in[5];
    const int*   nid = (const int*)d_in[6];
    const int*   src = (const int*)d_in[7];
    const int*   dst = (const int*)d_in[8];
    const int*   cur = (const int*)d_in[9];
    const float* aW2 = (const float*)d_in[10];
    const float* ab2 = (const float*)d_in[11];
    const float* aW3 = (const float*)d_in[12];
    const float* ab3 = (const float*)d_in[13];
    const float* aW4 = (const float*)d_in[14];
    const float* ab4 = (const float*)d_in[15];
    const float* cW2 = (const float*)d_in[16];
    const float* cb2 = (const float*)d_in[17];
    const float* cW3 = (const float*)d_in[18];
    const float* cb3 = (const float*)d_in[19];
    const float* cW4 = (const float*)d_in[20];
    const float* cb4 = (const float*)d_in[21];

    int n = in_sizes[0];
    int E = in_sizes[7];
    float* out = (float*)d_out;

    int nb  = (n + 4095) >> 12;                       // buckets of 4096 nodes
    int cap = E / (nb > 0 ? nb : 1) + 8192;           // >22 sigma slack
    int nbk = (n + 255) / 256;

    char* ws = (char*)d_ws;
    float4* featA  = (float4*)ws;                     // 16n
    u64*    packed = (u64*)(ws + (size_t)16 * n);     // 8n
    u64*    S2rep  = (u64*)(ws + (size_t)24 * n);     // 8n * NSL

    size_t tailsz = 256 + 8192 + (size_t)48 * nbk;

    // choose NSL: 8 if workspace allows, else 4, else fallback path
    int NSL = 8;
    size_t tail_off = (size_t)(24 + 8 * NSL) * n;
    size_t needed = tail_off + tailsz + (size_t)nb * cap * 4;
    if (ws_size < needed || nb > 128) {
        NSL = 4;
        tail_off = (size_t)(24 + 8 * NSL) * n;
        needed = tail_off + tailsz + (size_t)nb * cap * 4;
    }
    bool bucketPath = (ws_size >= needed) && (nb <= 128);
    size_t tail_fb = (size_t)32 * n;

    char* base = ws + (bucketPath ? tail_off : tail_fb);
    float* accum     = (float*)base;                              // 256 B
    u32*   bucketPos = (u32*)(base + 256);                        // 8192 B padded
    float* partials  = (float*)(base + 256 + 8192);               // 32*nbk B
    float* partials2 = (float*)(base + 256 + 8192 + (size_t)32 * nbk); // 16*nbk B
    u32*   records   = (u32*)(base + tailsz);

    if (bucketPath) {
        hipMemsetAsync(bucketPos, 0, 8192, stream);
        k1_prep<<<nbk, 256, 0, stream>>>(hop, rd, ett, ct, c2n, c2t, featA, packed, partials, n);
        k1b_reduce<<<1, 256, 0, stream>>>(partials, accum, nbk);
        int nchunks = (E + CHUNK - 1) / CHUNK;
        k2a_sort<<<nchunks, 256, 0, stream>>>(src, dst, records, bucketPos, E, nb, cap);
        k2b_accum<<<nb * NSL, 256, 0, stream>>>(records, bucketPos, packed, S2rep, n, cap, NSL);
        k3_mlp<<<nbk, 256, 0, stream>>>(featA, ct, S2rep, NSL, nid, cur,
                                        aW2, ab2, aW3, ab3, aW4, ab4, accum, partials2, out, n);
        k3b_reduce<<<1, 256, 0, stream>>>(partials2, accum, nbk);
    } else {
        u64* S2f = (u64*)(ws + (size_t)24 * n);
        hipMemsetAsync(S2f, 0, (size_t)8 * n, stream);
        k1_prep<<<nbk, 256, 0, stream>>>(hop, rd, ett, ct, c2n, c2t, featA, packed, partials, n);
        k1b_reduce<<<1, 256, 0, stream>>>(partials, accum, nbk);
        k2_atomic<<<4096, 256, 0, stream>>>(src, dst, packed, S2f, E);
        k3_mlp<<<nbk, 256, 0, stream>>>(featA, ct, S2f, 1, nid, cur,
                                        aW2, ab2, aW3, ab3, aW4, ab4, accum, partials2, out, n);
        k3b_reduce<<<1, 256, 0, stream>>>(partials2, accum, nbk);
    }
    k4_critic<<<1, 128, 0, stream>>>(accum, cW2, cb2, cW3, cb3, cW4, cb4, out, n);
    k5_scale<<<nbk, 256, 0, stream>>>(out, accum, n);
}

// Round 22
// 251.558 us; speedup vs baseline: 1.2947x; 1.0532x over previous
//
#include <hip/hip_runtime.h>
#include <hip/hip_bf16.h>

// ---------------------------------------------------------------------------
// PPO Actor-Critic GNN on MI355X.
// Round 22: consolidate at best-measured config (NSL=4) + one cut: k2a now
// register-caches the dst chunk (8 int4/thread) so pass B reuses regs and
// only loads src - removes the 2nd dst read chain. k2b keeps 8-way unroll.
// k2a = counting-sort scatter (35KB LDS, 4 blk/CU); k3 = fp8 MFMA (40KB);
// scalar reductions via partials (no same-line global atomics, r10/11).
// ---------------------------------------------------------------------------

typedef unsigned int u32;
typedef unsigned long long u64;
typedef long long i64t;
typedef __attribute__((ext_vector_type(4))) float f32x4;

#define BP_STRIDE 16   // bucketPos padding: 16 u32 = 64B per counter
#define CHUNK 8192

__device__ __forceinline__ float sigf(float x) { return 1.0f / (1.0f + __expf(-x)); }

__device__ __forceinline__ float waveReduceSum(float v) {
#pragma unroll
    for (int off = 32; off > 0; off >>= 1) v += __shfl_down(v, off, 64);
    return v;
}
__device__ __forceinline__ float waveReduceMax(float v) {
#pragma unroll
    for (int off = 32; off > 0; off >>= 1) v = fmaxf(v, __shfl_down(v, off, 64));
    return v;
}

// accum layout (floats):
// [0] max|hop| [1] max|cos| [2] max|rd| [3] max|ett|
// [4] sum ct   [5] sum hop  [6] sum rd
// [7] sum exp(policy)
// [8] sum x_ct  [9] sum x_hop_norm  [10] sum x_rd_norm

__global__ __launch_bounds__(256) void k1_prep(
    const float* __restrict__ hop, const float* __restrict__ rd,
    const float* __restrict__ ett, const float* __restrict__ ct,
    const float* __restrict__ c2n, const float* __restrict__ c2t,
    float4* __restrict__ featA, u64* __restrict__ packed,
    float* __restrict__ partials, int n)
{
    int i = blockIdx.x * blockDim.x + threadIdx.x;
    float ah = 0.f, ac = 0.f, ar = 0.f, ae = 0.f, sc = 0.f, sh = 0.f, sr = 0.f;
    if (i < n) {
        float h = hop[i], r = rd[i], e = ett[i], c = ct[i];
        float ax = c2n[3*i+0], ay = c2n[3*i+1], az = c2n[3*i+2];
        float bx = c2t[3*i+0], by = c2t[3*i+1], bz = c2t[3*i+2];
        float dot = ax*bx + ay*by + az*bz;
        float na = fmaxf(sqrtf(ax*ax + ay*ay + az*az), 1e-6f);
        float nb = fmaxf(sqrtf(bx*bx + by*by + bz*bz), 1e-6f);
        float cs = dot / (na * nb);
        featA[i] = make_float4(h, cs, r, e);

        // single-u64 fixed-point pack, scale 16
        // fields: ct 11b | hop 11b | cos+1 12b | rd 11b | ett 11b | deg 8b
        u64 qc = (u64)(u32)rintf(c * (16.0f/1440.0f));
        u64 qh = (u64)(u32)rintf(h * 16.0f);
        u64 qs = (u64)(u32)rintf((cs + 1.0f) * 16.0f);
        u64 qr = (u64)(u32)rintf(r * 16.0f);
        u64 qe = (u64)(u32)rintf(e * 16.0f);
        packed[i] = qc | (qh << 11) | (qs << 22) | (qr << 34) | (qe << 45) | (1ULL << 56);

        ah = fabsf(h); ac = fabsf(cs); ar = fabsf(r); ae = fabsf(e);
        sc = c; sh = h; sr = r;
    }
    ah = waveReduceMax(ah); ac = waveReduceMax(ac);
    ar = waveReduceMax(ar); ae = waveReduceMax(ae);
    sc = waveReduceSum(sc); sh = waveReduceSum(sh); sr = waveReduceSum(sr);

    __shared__ float red[4][7];
    int wid = threadIdx.x >> 6;
    if ((threadIdx.x & 63) == 0) {
        red[wid][0] = ah; red[wid][1] = ac; red[wid][2] = ar; red[wid][3] = ae;
        red[wid][4] = sc; red[wid][5] = sh; red[wid][6] = sr;
    }
    __syncthreads();
    if (threadIdx.x == 0) {
        float* p = partials + (size_t)blockIdx.x * 8;
        p[0] = fmaxf(fmaxf(red[0][0], red[1][0]), fmaxf(red[2][0], red[3][0]));
        p[1] = fmaxf(fmaxf(red[0][1], red[1][1]), fmaxf(red[2][1], red[3][1]));
        p[2] = fmaxf(fmaxf(red[0][2], red[1][2]), fmaxf(red[2][2], red[3][2]));
        p[3] = fmaxf(fmaxf(red[0][3], red[1][3]), fmaxf(red[2][3], red[3][3]));
        p[4] = red[0][4] + red[1][4] + red[2][4] + red[3][4];
        p[5] = red[0][5] + red[1][5] + red[2][5] + red[3][5];
        p[6] = red[0][6] + red[1][6] + red[2][6] + red[3][6];
    }
}

__global__ __launch_bounds__(256) void k1b_reduce(
    const float* __restrict__ partials, float* __restrict__ accum, int nblocks)
{
    float mh = 0.f, mc = 0.f, mr = 0.f, me = 0.f, sc = 0.f, sh = 0.f, sr = 0.f;
    for (int b = threadIdx.x; b < nblocks; b += 256) {
        const float* p = partials + (size_t)b * 8;
        mh = fmaxf(mh, p[0]); mc = fmaxf(mc, p[1]);
        mr = fmaxf(mr, p[2]); me = fmaxf(me, p[3]);
        sc += p[4]; sh += p[5]; sr += p[6];
    }
    mh = waveReduceMax(mh); mc = waveReduceMax(mc);
    mr = waveReduceMax(mr); me = waveReduceMax(me);
    sc = waveReduceSum(sc); sh = waveReduceSum(sh); sr = waveReduceSum(sr);
    __shared__ float red[4][7];
    int wid = threadIdx.x >> 6;
    if ((threadIdx.x & 63) == 0) {
        red[wid][0] = mh; red[wid][1] = mc; red[wid][2] = mr; red[wid][3] = me;
        red[wid][4] = sc; red[wid][5] = sh; red[wid][6] = sr;
    }
    __syncthreads();
    if (threadIdx.x == 0) {
        accum[0] = fmaxf(fmaxf(red[0][0], red[1][0]), fmaxf(red[2][0], red[3][0]));
        accum[1] = fmaxf(fmaxf(red[0][1], red[1][1]), fmaxf(red[2][1], red[3][1]));
        accum[2] = fmaxf(fmaxf(red[0][2], red[1][2]), fmaxf(red[2][2], red[3][2]));
        accum[3] = fmaxf(fmaxf(red[0][3], red[1][3]), fmaxf(red[2][3], red[3][3]));
        accum[4] = red[0][4] + red[1][4] + red[2][4] + red[3][4];
        accum[5] = red[0][5] + red[1][5] + red[2][5] + red[3][5];
        accum[6] = red[0][6] + red[1][6] + red[2][6] + red[3][6];
    }
}

// ---- Phase A: block-level counting sort -> coalesced bucket runs ---------
// records[b*cap + slot] = (src << 12) | (dst & 4095),  bucket b = dst >> 12
// Each thread owns 8 int4 slots: dst cached in registers across passes.
__global__ __launch_bounds__(256) void k2a_sort(
    const int* __restrict__ src, const int* __restrict__ dst,
    u32* __restrict__ records, u32* __restrict__ bucketPos,
    int E, int nb, int cap)
{
    __shared__ u32 hist[128];
    __shared__ u32 hoff[128];
    __shared__ u32 lstart[129];   // +1 sentinel
    __shared__ u32 gbase[128];
    __shared__ u32 sorted[CHUNK];          // 32 KB

    int tid = threadIdx.x;
    int e0 = blockIdx.x * CHUNK;
    int cnt = min(CHUNK, E - e0);
    if (cnt <= 0) return;
    int cnt4 = cnt >> 2;
    const int4* dst4 = (const int4*)(dst + e0);
    const int4* src4 = (const int4*)(src + e0);

    for (int i = tid; i < nb; i += 256) { hist[i] = 0; hoff[i] = 0; }
    __syncthreads();

    // pass A: load dst into registers + histogram
    int4 dreg[8];
#pragma unroll
    for (int k = 0; k < 8; ++k) {
        int idx = tid + k * 256;
        if (idx < cnt4) {
            int4 d = dst4[idx];
            dreg[k] = d;
            atomicAdd(&hist[d.x >> 12], 1u);
            atomicAdd(&hist[d.y >> 12], 1u);
            atomicAdd(&hist[d.z >> 12], 1u);
            atomicAdd(&hist[d.w >> 12], 1u);
        }
    }
    for (int i = (cnt4 << 2) + tid; i < cnt; i += 256)
        atomicAdd(&hist[dst[e0 + i] >> 12], 1u);
    __syncthreads();

    // prefix scan (serial over nb) + sentinel; global reserve (padded counters)
    if (tid == 0) {
        u32 run = 0;
        for (int b = 0; b < nb; ++b) { lstart[b] = run; run += hist[b]; }
        lstart[nb] = run;   // == cnt
    }
    __syncthreads();
    for (int b = tid; b < nb; b += 256)
        gbase[b] = atomicAdd(&bucketPos[b * BP_STRIDE], hist[b]);
    __syncthreads();

    // pass B: scatter into LDS (dst from registers, load src only)
#pragma unroll
    for (int k = 0; k < 8; ++k) {
        int idx = tid + k * 256;
        if (idx < cnt4) {
            int4 s = src4[idx];
            int4 d = dreg[k];
            {
                u32 b = (u32)d.x >> 12;
                u32 ls = lstart[b] + atomicAdd(&hoff[b], 1u);
                sorted[ls] = ((u32)s.x << 12) | ((u32)d.x & 4095u);
            }
            {
                u32 b = (u32)d.y >> 12;
                u32 ls = lstart[b] + atomicAdd(&hoff[b], 1u);
                sorted[ls] = ((u32)s.y << 12) | ((u32)d.y & 4095u);
            }
            {
                u32 b = (u32)d.z >> 12;
                u32 ls = lstart[b] + atomicAdd(&hoff[b], 1u);
                sorted[ls] = ((u32)s.z << 12) | ((u32)d.z & 4095u);
            }
            {
                u32 b = (u32)d.w >> 12;
                u32 ls = lstart[b] + atomicAdd(&hoff[b], 1u);
                sorted[ls] = ((u32)s.w << 12) | ((u32)d.w & 4095u);
            }
        }
    }
    for (int i = (cnt4 << 2) + tid; i < cnt; i += 256) {
        int d = dst[e0 + i];
        u32 b = (u32)d >> 12;
        u32 ls = lstart[b] + atomicAdd(&hoff[b], 1u);
        sorted[ls] = ((u32)src[e0 + i] << 12) | ((u32)d & 4095u);
    }
    __syncthreads();

    // pass C: per-wave bucket-run copy (coalesced, no per-record lookup)
    int wid = tid >> 6;
    int lane = tid & 63;
    for (int b = wid; b < nb; b += 4) {
        u32 s0 = lstart[b];
        u32 s1 = lstart[b + 1];
        u32 gb = gbase[b];
        u32* dstrec = records + (size_t)b * cap;
        for (u32 i = s0 + lane; i < s1; i += 64) {
            u32 pos = gb + (i - s0);
            if (pos < (u32)cap) dstrec[pos] = sorted[i];
        }
    }
}

// ---- Phase B: LDS accumulate + replica flush (bucket x slice grid) -------
__global__ __launch_bounds__(256) void k2b_accum(
    const u32* __restrict__ records, const u32* __restrict__ bucketPos,
    const u64* __restrict__ packed, u64* __restrict__ S2rep,
    int n, int cap, int nsl)
{
    __shared__ u64 acc[4096];   // 32 KB
    int bucket = blockIdx.x / nsl;
    int slice  = blockIdx.x % nsl;
    int nodeBase = bucket << 12;
    int nNodes = min(4096, n - nodeBase);
    for (int i = threadIdx.x; i < 4096; i += 256) acc[i] = 0;
    __syncthreads();
    u32 cnt = bucketPos[bucket * BP_STRIDE];
    if (cnt > (u32)cap) cnt = (u32)cap;
    u32 lo = (u32)(((u64)cnt * (u32)slice) / (u32)nsl);
    u32 hi = (u32)(((u64)cnt * (u32)(slice + 1)) / (u32)nsl);
    const u32* rec = records + (size_t)bucket * cap;
    u32 r = lo + threadIdx.x;
    // 8-way unrolled independent gather chains
    for (; r + 1792 < hi; r += 2048) {
        u32 v0 = rec[r];
        u32 v1 = rec[r + 256];
        u32 v2 = rec[r + 512];
        u32 v3 = rec[r + 768];
        u32 v4 = rec[r + 1024];
        u32 v5 = rec[r + 1280];
        u32 v6 = rec[r + 1536];
        u32 v7 = rec[r + 1792];
        u64 p0 = packed[v0 >> 12];
        u64 p1 = packed[v1 >> 12];
        u64 p2 = packed[v2 >> 12];
        u64 p3 = packed[v3 >> 12];
        u64 p4 = packed[v4 >> 12];
        u64 p5 = packed[v5 >> 12];
        u64 p6 = packed[v6 >> 12];
        u64 p7 = packed[v7 >> 12];
        atomicAdd(&acc[v0 & 4095u], p0);
        atomicAdd(&acc[v1 & 4095u], p1);
        atomicAdd(&acc[v2 & 4095u], p2);
        atomicAdd(&acc[v3 & 4095u], p3);
        atomicAdd(&acc[v4 & 4095u], p4);
        atomicAdd(&acc[v5 & 4095u], p5);
        atomicAdd(&acc[v6 & 4095u], p6);
        atomicAdd(&acc[v7 & 4095u], p7);
    }
    for (; r < hi; r += 256) {
        u32 v = rec[r];
        atomicAdd(&acc[v & 4095u], packed[v >> 12]);
    }
    __syncthreads();
    u64* dstp = S2rep + (size_t)slice * n + nodeBase;
    for (int i = threadIdx.x; i < nNodes; i += 256) dstp[i] = acc[i];
}

// ---- K3: actor MLP, fp8 MFMA layer-3, 40KB LDS ---------------------------
__global__ __launch_bounds__(256, 4) void k3_mlp(
    const float4* __restrict__ featA, const float* __restrict__ ct,
    const u64* __restrict__ S2rep, int nsl, const int* __restrict__ nid,
    const int* __restrict__ currp,
    const float* __restrict__ aW2, const float* __restrict__ ab2,
    const float* __restrict__ aW3, const float* __restrict__ ab3,
    const float* __restrict__ aW4, const float* __restrict__ ab4,
    const float* __restrict__ accum, float* __restrict__ partials2,
    float* __restrict__ out, int n)
{
    __shared__ char w3t8[8192];    // fp8 W3t[col 64][j 128], 16B-XOR-swz by col&7
    __shared__ char hb8[32768];    // fp8 h[node 256][j 128], 16B-XOR-swz by row&7

    int tid  = threadIdx.x;
    int lane = tid & 63;
    int wid  = tid >> 6;
    int lc   = lane & 15;
    int lg   = lane >> 4;

    // ---- stage W3 transposed -> fp8, swizzled ----
    for (int t = tid; t < 2048; t += 256) {
        int col = t & 63;
        int j0  = (t >> 6) << 2;     // 0,4,...,124
        float w0 = aW3[(j0 + 0) * 64 + col];
        float w1 = aW3[(j0 + 1) * 64 + col];
        float w2 = aW3[(j0 + 2) * 64 + col];
        float w3 = aW3[(j0 + 3) * 64 + col];
        u32 pk = (u32)__builtin_amdgcn_cvt_pk_fp8_f32(w0, w1, 0, false);
        pk = (u32)__builtin_amdgcn_cvt_pk_fp8_f32(w2, w3, (int)pk, true);
        *(u32*)(w3t8 + col * 128 + (j0 ^ ((col & 7) << 4))) = pk;
    }

    int i0 = blockIdx.x * 256 + tid;
    int i = i0 < n ? i0 : n - 1;           // clamp: no divergence in compute
    bool valid = i0 < n;

    float inv_mh = 1.0f / fmaxf(accum[0], 1e-12f);
    float inv_mc = 1.0f / fmaxf(accum[1], 1e-12f);
    float inv_mr = 1.0f / fmaxf(accum[2], 1e-12f);
    float inv_me = 1.0f / fmaxf(accum[3], 1e-12f);
    int curr = currp[0];

    float4 f = featA[i];
    float c = ct[i];
    u64 P = 0;
    for (int s = 0; s < nsl; ++s) P += S2rep[(size_t)s * n + i];
    u32 qct = (u32)(P         & 0x7FFULL);
    u32 qh  = (u32)((P >> 11) & 0x7FFULL);
    u32 qcs = (u32)((P >> 22) & 0xFFFULL);
    u32 qr  = (u32)((P >> 34) & 0x7FFULL);
    u32 qe  = (u32)((P >> 45) & 0x7FFULL);
    u32 deg = (u32)(P >> 56);
    float icd = deg ? 1.0f / (16.0f * (float)deg) : 0.f;
    float x0 = (float)qct * icd;
    float x1 = (float)qh  * icd * inv_mh;
    float x2 = deg ? ((float)qcs * icd - 1.0f) * inv_mc : 0.f;
    float x3 = (float)qr  * icd * inv_mr;
    float x4 = (float)qe  * icd * inv_me;
    float f0 = c * (1.0f/1440.0f);
    float f1 = f.x * inv_mh, f2 = f.y * inv_mc, f3 = f.z * inv_mr, f4 = f.w * inv_me;
    float g0 = 0.5f*(f0+x0), g1 = 0.5f*(f1+x1), g2 = 0.5f*(f2+x2),
          g3 = 0.5f*(f3+x3), g4 = 0.5f*(f4+x4);

    // ---- phase 1: layer 2 (5->128) + sigmoid -> fp8 -> hb8 ----
    {
        int rowbase = tid * 128;
        int swz = (tid & 7) << 4;
        for (int j = 0; j < 128; j += 16) {
            float hv[16];
#pragma unroll
            for (int jj = 0; jj < 16; ++jj) {
                float t = ab2[j + jj];
                t = fmaf(g0, aW2[j + jj],       t);
                t = fmaf(g1, aW2[128 + j + jj], t);
                t = fmaf(g2, aW2[256 + j + jj], t);
                t = fmaf(g3, aW2[384 + j + jj], t);
                t = fmaf(g4, aW2[512 + j + jj], t);
                float e = __expf(-t);
                hv[jj] = __builtin_amdgcn_rcpf(1.0f + e);
            }
            int4 w;
            u32 a;
            a = (u32)__builtin_amdgcn_cvt_pk_fp8_f32(hv[0],  hv[1],  0, false);
            a = (u32)__builtin_amdgcn_cvt_pk_fp8_f32(hv[2],  hv[3],  (int)a, true);
            w.x = (int)a;
            a = (u32)__builtin_amdgcn_cvt_pk_fp8_f32(hv[4],  hv[5],  0, false);
            a = (u32)__builtin_amdgcn_cvt_pk_fp8_f32(hv[6],  hv[7],  (int)a, true);
            w.y = (int)a;
            a = (u32)__builtin_amdgcn_cvt_pk_fp8_f32(hv[8],  hv[9],  0, false);
            a = (u32)__builtin_amdgcn_cvt_pk_fp8_f32(hv[10], hv[11], (int)a, true);
            w.z = (int)a;
            a = (u32)__builtin_amdgcn_cvt_pk_fp8_f32(hv[12], hv[13], 0, false);
            a = (u32)__builtin_amdgcn_cvt_pk_fp8_f32(hv[14], hv[15], (int)a, true);
            w.w = (int)a;
            *(int4*)(hb8 + rowbase + (j ^ swz)) = w;
        }
    }
    __syncthreads();

    // ---- phase 2: layer 3 (128->64) via fp8 MFMA + layer 4 ----
    i64t bfr[4][4];
#pragma unroll
    for (int nt = 0; nt < 4; ++nt) {
#pragma unroll
        for (int kc = 0; kc < 4; ++kc) {
            int col = nt * 16 + lc;
            int boff = col * 128 + ((kc * 32 + lg * 8) ^ ((col & 7) << 4));
            bfr[nt][kc] = *(const i64t*)(w3t8 + boff);
        }
    }
    float b3v[4], w4v[4];
#pragma unroll
    for (int nt = 0; nt < 4; ++nt) {
        b3v[nt] = ab3[nt * 16 + lc];
        w4v[nt] = aW4[nt * 16 + lc];
    }
    float bias4 = ab4[0];

    int waveSlot = wid * 64;
    float evloc = 0.f;
#pragma unroll
    for (int mt = 0; mt < 4; ++mt) {
        i64t afr[4];
#pragma unroll
        for (int kc = 0; kc < 4; ++kc) {
            int row = waveSlot + mt * 16 + lc;
            int aoff = row * 128 + ((kc * 32 + lg * 8) ^ ((row & 7) << 4));
            afr[kc] = *(const i64t*)(hb8 + aoff);
        }
        float ps0 = 0.f, ps1 = 0.f, ps2 = 0.f, ps3 = 0.f;
#pragma unroll
        for (int nt = 0; nt < 4; ++nt) {
            f32x4 d = {0.f, 0.f, 0.f, 0.f};
            d = __builtin_amdgcn_mfma_f32_16x16x32_fp8_fp8(afr[0], bfr[nt][0], d, 0, 0, 0);
            d = __builtin_amdgcn_mfma_f32_16x16x32_fp8_fp8(afr[1], bfr[nt][1], d, 0, 0, 0);
            d = __builtin_amdgcn_mfma_f32_16x16x32_fp8_fp8(afr[2], bfr[nt][2], d, 0, 0, 0);
            d = __builtin_amdgcn_mfma_f32_16x16x32_fp8_fp8(afr[3], bfr[nt][3], d, 0, 0, 0);
            float b3 = b3v[nt], w4 = w4v[nt];
            ps0 = fmaf(sigf(d[0] + b3), w4, ps0);
            ps1 = fmaf(sigf(d[1] + b3), w4, ps1);
            ps2 = fmaf(sigf(d[2] + b3), w4, ps2);
            ps3 = fmaf(sigf(d[3] + b3), w4, ps3);
        }
#pragma unroll
        for (int off = 1; off < 16; off <<= 1) {
            ps0 += __shfl_xor(ps0, off, 64);
            ps1 += __shfl_xor(ps1, off, 64);
            ps2 += __shfl_xor(ps2, off, 64);
            ps3 += __shfl_xor(ps3, off, 64);
        }
        if (lc < 4) {
            float pv = (lc == 0) ? ps0 : (lc == 1) ? ps1 : (lc == 2) ? ps2 : ps3;
            pv += bias4;
            int slot = waveSlot + mt * 16 + lg * 4 + lc;   // D row = lg*4 + reg
            int gi = blockIdx.x * 256 + slot;
            if (gi < n) {
                float evv = (nid[gi] == curr) ? 0.f : __expf(pv);
                out[gi] = evv;
                evloc += evv;
            }
        }
    }

    float r0s = valid ? x0 : 0.f;
    float r1s = valid ? x1 : 0.f;
    float r3s = valid ? x3 : 0.f;

    float ev = waveReduceSum(evloc);
    r0s = waveReduceSum(r0s);
    r1s = waveReduceSum(r1s);
    r3s = waveReduceSum(r3s);

    __syncthreads();   // all hb8 reads done -> safe to reuse as red[]
    float (*red)[4] = (float(*)[4])hb8;
    if ((tid & 63) == 0) {
        red[wid][0] = ev; red[wid][1] = r0s; red[wid][2] = r1s; red[wid][3] = r3s;
    }
    __syncthreads();
    if (tid == 0) {
        float* p2 = partials2 + (size_t)blockIdx.x * 4;
        p2[0] = red[0][0] + red[1][0] + red[2][0] + red[3][0];
        p2[1] = red[0][1] + red[1][1] + red[2][1] + red[3][1];
        p2[2] = red[0][2] + red[1][2] + red[2][2] + red[3][2];
        p2[3] = red[0][3] + red[1][3] + red[2][3] + red[3][3];
    }
}

__global__ __launch_bounds__(256) void k3b_reduce(
    const float* __restrict__ partials2, float* __restrict__ accum, int nblocks)
{
    float s0 = 0.f, s1 = 0.f, s2 = 0.f, s3 = 0.f;
    for (int b = threadIdx.x; b < nblocks; b += 256) {
        const float* p = partials2 + (size_t)b * 4;
        s0 += p[0]; s1 += p[1]; s2 += p[2]; s3 += p[3];
    }
    s0 = waveReduceSum(s0); s1 = waveReduceSum(s1);
    s2 = waveReduceSum(s2); s3 = waveReduceSum(s3);
    __shared__ float red[4][4];
    int wid = threadIdx.x >> 6;
    if ((threadIdx.x & 63) == 0) {
        red[wid][0] = s0; red[wid][1] = s1; red[wid][2] = s2; red[wid][3] = s3;
    }
    __syncthreads();
    if (threadIdx.x == 0) {
        accum[7]  = red[0][0] + red[1][0] + red[2][0] + red[3][0];
        accum[8]  = red[0][1] + red[1][1] + red[2][1] + red[3][1];
        accum[9]  = red[0][2] + red[1][2] + red[2][2] + red[3][2];
        accum[10] = red[0][3] + red[1][3] + red[2][3] + red[3][3];
    }
}

__global__ void k4_critic(const float* __restrict__ accum,
                          const float* __restrict__ cW2, const float* __restrict__ cb2,
                          const float* __restrict__ cW3, const float* __restrict__ cb3,
                          const float* __restrict__ cW4, const float* __restrict__ cb4,
                          float* __restrict__ out, int n)
{
    __shared__ float v1[128];
    __shared__ float v2[64];
    int t = threadIdx.x;
    float invN = 1.0f / (float)n;
    float inv_mh = 1.0f / fmaxf(accum[0], 1e-12f);
    float inv_mr = 1.0f / fmaxf(accum[2], 1e-12f);
    float cx0 = accum[4] * invN * (1.0f / 1440.0f);
    float cx1 = accum[5] * invN * inv_mh;
    float cx2 = accum[6] * invN * inv_mr;
    float cx3 = accum[8] * invN;
    float cx4 = accum[9] * invN;
    float cx5 = accum[10] * invN;
    if (t < 128) {
        float a = cb2[t];
        a = fmaf(cx0, cW2[t],       a);
        a = fmaf(cx1, cW2[128 + t], a);
        a = fmaf(cx2, cW2[256 + t], a);
        a = fmaf(cx3, cW2[384 + t], a);
        a = fmaf(cx4, cW2[512 + t], a);
        a = fmaf(cx5, cW2[640 + t], a);
        v1[t] = sigf(a);
    }
    __syncthreads();
    if (t < 64) {
        float a = cb3[t];
        for (int j = 0; j < 128; ++j) a = fmaf(v1[j], cW3[j * 64 + t], a);
        v2[t] = sigf(a);
    }
    __syncthreads();
    if (t == 0) {
        float a = cb4[0];
        for (int k = 0; k < 64; ++k) a = fmaf(v2[k], cW4[k], a);
        out[n] = a;  // value
    }
}

__global__ void k5_scale(float* __restrict__ out, const float* __restrict__ accum, int n)
{
    int i = blockIdx.x * blockDim.x + threadIdx.x;
    float inv = 1.0f / accum[7];
    if (i < n) out[i] *= inv;
}

// fallback: one global u64 atomic per edge
__global__ void k2_atomic(const int* __restrict__ src, const int* __restrict__ dst,
                          const u64* __restrict__ packed, u64* __restrict__ S2, int E)
{
    int stride = gridDim.x * blockDim.x;
    for (int e = blockIdx.x * blockDim.x + threadIdx.x; e < E; e += stride) {
        atomicAdd(S2 + dst[e], packed[src[e]]);
    }
}

extern "C" void kernel_launch(void* const* d_in, const int* in_sizes, int n_in,
                              void* d_out, int out_size, void* d_ws, size_t ws_size,
                              hipStream_t stream)
{
    const float* hop = (const float*)d_in[0];
    const float* rd  = (const float*)d_in[1];
    const float* ett = (const float*)d_in[2];
    const float* ct  = (const float*)d_in[3];
    const float* c2n = (const float*)d_in[4];
    const float* c2t = (const float*)d_in[5];
    const int*   nid = (const int*)d_in[6];
    const int*   src = (const int*)d_in[7];
    const int*   dst = (const int*)d_in[8];
    const int*   cur = (const int*)d_in[9];
    const float* aW2 = (const float*)d_in[10];
    const float* ab2 = (const float*)d_in[11];
    const float* aW3 = (const float*)d_in[12];
    const float* ab3 = (const float*)d_in[13];
    const float* aW4 = (const float*)d_in[14];
    const float* ab4 = (const float*)d_in[15];
    const float* cW2 = (const float*)d_in[16];
    const float* cb2 = (const float*)d_in[17];
    const float* cW3 = (const float*)d_in[18];
    const float* cb3 = (const float*)d_in[19];
    const float* cW4 = (const float*)d_in[20];
    const float* cb4 = (const float*)d_in[21];

    int n = in_sizes[0];
    int E = in_sizes[7];
    float* out = (float*)d_out;

    const int NSL = 4;
    int nb  = (n + 4095) >> 12;                       // buckets of 4096 nodes
    int cap = E / (nb > 0 ? nb : 1) + 8192;           // >22 sigma slack
    int nbk = (n + 255) / 256;

    char* ws = (char*)d_ws;
    float4* featA  = (float4*)ws;                     // 16n
    u64*    packed = (u64*)(ws + (size_t)16 * n);     // 8n
    u64*    S2rep  = (u64*)(ws + (size_t)24 * n);     // 8n * NSL = 32n

    size_t tail_bucket = (size_t)56 * n;
    size_t tail_fb     = (size_t)32 * n;
    size_t tailsz = 256 + 8192 + (size_t)48 * nbk;
    size_t needed = tail_bucket + tailsz + (size_t)nb * cap * 4;
    bool bucketPath = (ws_size >= needed) && (nb <= 128);

    char* base = ws + (bucketPath ? tail_bucket : tail_fb);
    float* accum     = (float*)base;                              // 256 B
    u32*   bucketPos = (u32*)(base + 256);                        // 8192 B padded
    float* partials  = (float*)(base + 256 + 8192);               // 32*nbk B
    float* partials2 = (float*)(base + 256 + 8192 + (size_t)32 * nbk); // 16*nbk B
    u32*   records   = (u32*)(base + tailsz);

    if (bucketPath) {
        hipMemsetAsync(bucketPos, 0, 8192, stream);
        k1_prep<<<nbk, 256, 0, stream>>>(hop, rd, ett, ct, c2n, c2t, featA, packed, partials, n);
        k1b_reduce<<<1, 256, 0, stream>>>(partials, accum, nbk);
        int nchunks = (E + CHUNK - 1) / CHUNK;
        k2a_sort<<<nchunks, 256, 0, stream>>>(src, dst, records, bucketPos, E, nb, cap);
        k2b_accum<<<nb * NSL, 256, 0, stream>>>(records, bucketPos, packed, S2rep, n, cap, NSL);
        k3_mlp<<<nbk, 256, 0, stream>>>(featA, ct, S2rep, NSL, nid, cur,
                                        aW2, ab2, aW3, ab3, aW4, ab4, accum, partials2, out, n);
        k3b_reduce<<<1, 256, 0, stream>>>(partials2, accum, nbk);
    } else {
        u64* S2f = (u64*)(ws + (size_t)24 * n);
        hipMemsetAsync(S2f, 0, (size_t)8 * n, stream);
        k1_prep<<<nbk, 256, 0, stream>>>(hop, rd, ett, ct, c2n, c2t, featA, packed, partials, n);
        k1b_reduce<<<1, 256, 0, stream>>>(partials, accum, nbk);
        k2_atomic<<<4096, 256, 0, stream>>>(src, dst, packed, S2f, E);
        k3_mlp<<<nbk, 256, 0, stream>>>(featA, ct, S2f, 1, nid, cur,
                                        aW2, ab2, aW3, ab3, aW4, ab4, accum, partials2, out, n);
        k3b_reduce<<<1, 256, 0, stream>>>(partials2, accum, nbk);
    }
    k4_critic<<<1, 128, 0, stream>>>(accum, cW2, cb2, cW3, cb3, cW4, cb4, out, n);
    k5_scale<<<nbk, 256, 0, stream>>>(out, accum, n);
}